// Round 1
// baseline (531.836 us; speedup 1.0000x reference)
//
#include <hip/hip_runtime.h>
#include <stdint.h>

#define B_ 1024
#define T_ 255
#define D_ 128
#define H_ 128
#define G_ 512   // 4*H

typedef float f32x4 __attribute__((ext_vector_type(4)));
typedef short s16x8 __attribute__((ext_vector_type(8)));

__device__ __forceinline__ unsigned short f32_bf16(float f){
  union { float f; unsigned u; } c; c.f = f;
  return (unsigned short)((c.u + 0x7fffu + ((c.u >> 16) & 1u)) >> 16);  // RNE
}
__device__ __forceinline__ float bf16_f32(unsigned short h){
  union { unsigned u; float f; } c; c.u = ((unsigned)h) << 16;
  return c.f;
}
__device__ __forceinline__ float sigm(float x){ return 1.f / (1.f + __expf(-x)); }
__device__ __forceinline__ float tanh_f(float x){ return 2.f / (1.f + __expf(-2.f * x)) - 1.f; }

// ---------------- Kernel 1: x_part + softmax -> attn[b][128] -------------
__global__ __launch_bounds__(256) void k_attn(const float* __restrict__ x,
                                              const float* __restrict__ Wa,
                                              float* __restrict__ attn){
  __shared__ float wxs[T_];
  __shared__ float part[256];
  __shared__ float xp[128];
  __shared__ float red[128];
  int tid = threadIdx.x, b = blockIdx.x;
  for (int t = tid; t < T_; t += 256) wxs[t] = Wa[2 * H_ + t];
  __syncthreads();
  int d = tid & 127, half = tid >> 7;
  const float* xb = x + (size_t)b * T_ * D_ + d;
  float acc = 0.f;
  for (int t = half; t < T_; t += 2) acc += xb[(size_t)t * D_] * wxs[t];
  part[tid] = acc;
  __syncthreads();
  if (tid < 128){ float v = part[tid] + part[tid + 128]; xp[tid] = v; red[tid] = v; }
  __syncthreads();
  for (int s = 64; s >= 1; s >>= 1){ if (tid < s) red[tid] = fmaxf(red[tid], red[tid + s]); __syncthreads(); }
  float mx = red[0];
  __syncthreads();
  float ev = 0.f;
  if (tid < 128){ ev = __expf(xp[tid] - mx); red[tid] = ev; }
  __syncthreads();
  for (int s = 64; s >= 1; s >>= 1){ if (tid < s) red[tid] += red[tid + s]; __syncthreads(); }
  float sm = red[0];
  if (tid < 128) attn[b * D_ + tid] = ev / sm;
}

// W (512x128 f32, row-major) -> LDS bf16 [n][k], XOR-swizzled 16B slots
__device__ __forceinline__ void fill_W_lds(char* lds, const float* __restrict__ W, int tid){
  for (int idx = tid; idx < G_ * 32; idx += 512){
    int n = idx >> 5, kq = idx & 31;                       // kq: float4 index in row
    float4 w4 = ((const float4*)(W + n * D_))[kq];
    unsigned off = ((unsigned)((n << 8) + (kq << 3))) ^ ((unsigned)(n & 7) << 4);
    unsigned lo = (unsigned)f32_bf16(w4.x) | ((unsigned)f32_bf16(w4.y) << 16);
    unsigned hi = (unsigned)f32_bf16(w4.z) | ((unsigned)f32_bf16(w4.w) << 16);
    *(uint2*)(lds + off) = make_uint2(lo, hi);
  }
}

// ---------------- Kernel 2: wx -> out0 ; G1 = wx@W_ih^T + b_ih + b_hh (bf16) ----
// grid 256: 32 b-tiles (32 rows) x 8 t-chunks (32 t). block 512 = 8 waves (wm 0..1, wn 0..3).
__global__ __launch_bounds__(512, 2) void k_gemm1(const float* __restrict__ x,
    const float* __restrict__ attn, const float* __restrict__ W_ih,
    const float* __restrict__ b_ih, const float* __restrict__ b_hh,
    float* __restrict__ out_w, unsigned short* __restrict__ g1){
  extern __shared__ char lds[];
  int tid = threadIdx.x;
  fill_W_lds(lds, W_ih, tid);
  int lane = tid & 63, w = tid >> 6;
  int wm = w >> 2, wn = w & 3;
  int l15 = lane & 15, lg = lane >> 4;
  int bx = blockIdx.x;
  int bt = bx & 31, tc = bx >> 5;
  int mrow = (bt << 5) + (wm << 4) + l15;
  int nbase = wn << 7;
  float afr[4][8];
  #pragma unroll
  for (int kt = 0; kt < 4; kt++){
    const float4* ap = (const float4*)(attn + mrow * D_ + kt * 32 + lg * 8);
    float4 a0 = ap[0], a1 = ap[1];
    afr[kt][0]=a0.x; afr[kt][1]=a0.y; afr[kt][2]=a0.z; afr[kt][3]=a0.w;
    afr[kt][4]=a1.x; afr[kt][5]=a1.y; afr[kt][6]=a1.z; afr[kt][7]=a1.w;
  }
  float biasr[8];
  #pragma unroll
  for (int nt = 0; nt < 8; nt++){
    int n = nbase + (nt << 4) + l15;
    biasr[nt] = b_ih[n] + b_hh[n];
  }
  __syncthreads();
  for (int i = 0; i < 32; i++){
    int t = (tc << 5) + i;
    if (t >= T_) break;
    const float* xrow = x + ((size_t)mrow * T_ + t) * D_;
    float* wrow = out_w + ((size_t)mrow * T_ + t) * D_;
    s16x8 af[4];
    #pragma unroll
    for (int kt = 0; kt < 4; kt++){
      int k0 = kt * 32 + lg * 8;
      const float4* xp4 = (const float4*)(xrow + k0);
      float4 x0 = xp4[0], x1 = xp4[1];
      float v0=x0.x*afr[kt][0], v1=x0.y*afr[kt][1], v2=x0.z*afr[kt][2], v3=x0.w*afr[kt][3];
      float v4=x1.x*afr[kt][4], v5=x1.y*afr[kt][5], v6=x1.z*afr[kt][6], v7=x1.w*afr[kt][7];
      if (wn == 0){                       // only one wave-column writes wx (dedup)
        float4* wp4 = (float4*)(wrow + k0);
        wp4[0] = make_float4(v0, v1, v2, v3);
        wp4[1] = make_float4(v4, v5, v6, v7);
      }
      s16x8 a;
      a[0]=(short)f32_bf16(v0); a[1]=(short)f32_bf16(v1); a[2]=(short)f32_bf16(v2); a[3]=(short)f32_bf16(v3);
      a[4]=(short)f32_bf16(v4); a[5]=(short)f32_bf16(v5); a[6]=(short)f32_bf16(v6); a[7]=(short)f32_bf16(v7);
      af[kt] = a;
    }
    f32x4 zero4 = {0.f, 0.f, 0.f, 0.f};
    f32x4 acc[8];
    #pragma unroll
    for (int nt = 0; nt < 8; nt++) acc[nt] = zero4;
    #pragma unroll
    for (int kt = 0; kt < 4; kt++){
      #pragma unroll
      for (int nt = 0; nt < 8; nt++){
        int n = nbase + (nt << 4) + l15;
        unsigned off = ((unsigned)((n << 8) + (kt << 6) + (lg << 4))) ^ ((unsigned)(n & 7) << 4);
        s16x8 bf = *(const s16x8*)(lds + off);
        acc[nt] = __builtin_amdgcn_mfma_f32_16x16x32_bf16(af[kt], bf, acc[nt], 0, 0, 0);
      }
    }
    size_t gbase = (size_t)t * B_;
    #pragma unroll
    for (int nt = 0; nt < 8; nt++){
      int n = nbase + (nt << 4) + l15;
      #pragma unroll
      for (int r = 0; r < 4; r++){
        int brow = (bt << 5) + (wm << 4) + (lg << 2) + r;   // D row=(lg)*4+r (verified layout)
        g1[(gbase + brow) * G_ + n] = f32_bf16(acc[nt][r] + biasr[nt]);
      }
    }
  }
}

// ---------------- Kernel 3: sequential recurrence, 4 batch rows / block ----------
// block 512 = 8 waves; wave w owns gate columns [w*64, w*64+64). W_hh held as reg B-frags.
__global__ __launch_bounds__(512, 2) void k_rnn(const float* __restrict__ W_hh,
    const unsigned short* __restrict__ g1, float* __restrict__ out_e){
  extern __shared__ char lds[];
  char*  g1l = lds;                    // 4 KB  bf16 [4][512]
  float* gl  = (float*)(lds + 4096);   // 8 KB  f32  [4][512]
  char*  hl  = lds + 4096 + 8192;      // 1 KB  bf16 [4][128] swizzled
  int tid = threadIdx.x;
  int lane = tid & 63, w = tid >> 6;
  int l15 = lane & 15, lg = lane >> 4;
  int b0 = blockIdx.x << 2;
  int r_c = tid >> 7, d_c = tid & 127;

  // W_hh B-fragments in registers: 16 frags (4 kt x 4 nt), same k-bijection as A side.
  s16x8 bfr[4][4];
  #pragma unroll
  for (int kt = 0; kt < 4; kt++){
    #pragma unroll
    for (int nt = 0; nt < 4; nt++){
      int n = (w << 6) + (nt << 4) + l15;
      const float4* wp = (const float4*)(W_hh + n * D_ + kt * 32 + lg * 8);
      float4 w0 = wp[0], w1 = wp[1];
      s16x8 bb;
      bb[0]=(short)f32_bf16(w0.x); bb[1]=(short)f32_bf16(w0.y); bb[2]=(short)f32_bf16(w0.z); bb[3]=(short)f32_bf16(w0.w);
      bb[4]=(short)f32_bf16(w1.x); bb[5]=(short)f32_bf16(w1.y); bb[6]=(short)f32_bf16(w1.z); bb[7]=(short)f32_bf16(w1.w);
      bfr[kt][nt] = bb;
    }
  }
  if (tid < 128) ((uint2*)hl)[tid] = make_uint2(0, 0);   // h0 = 0
  float c_st = 0.f;
  const uint2* g1g = (const uint2*)(g1 + (size_t)b0 * G_);
  uint2 g1r = g1g[tid];                                   // prefetch t=0 tile (4 KB)
  __syncthreads();

  s16x8 zero8 = {0,0,0,0,0,0,0,0};
  f32x4 zero4 = {0.f,0.f,0.f,0.f};
  for (int t = 0; t < T_; t++){
    *(uint2*)(g1l + tid * 8) = g1r;                       // publish G1(t)
    if (t + 1 < T_) g1r = g1g[(size_t)(t + 1) * (B_ * G_ / 4) + tid];  // prefetch G1(t+1)
    // A-frags from h LDS (rows 0..3 valid, rest zero)
    s16x8 af[4];
    bool val = (l15 < 4);
    #pragma unroll
    for (int kt = 0; kt < 4; kt++){
      if (val){
        unsigned off = ((unsigned)((l15 << 8) + (kt << 6) + (lg << 4))) ^ ((unsigned)l15 << 4);
        af[kt] = *(const s16x8*)(hl + off);
      } else af[kt] = zero8;
    }
    f32x4 acc[4];
    #pragma unroll
    for (int nt = 0; nt < 4; nt++) acc[nt] = zero4;
    #pragma unroll
    for (int kt = 0; kt < 4; kt++){
      #pragma unroll
      for (int nt = 0; nt < 4; nt++)
        acc[nt] = __builtin_amdgcn_mfma_f32_16x16x32_bf16(af[kt], bfr[kt][nt], acc[nt], 0, 0, 0);
    }
    if (lane < 16){                                       // rows 0..3 live in lanes 0..15
      #pragma unroll
      for (int nt = 0; nt < 4; nt++){
        int n = (w << 6) + (nt << 4) + lane;
        #pragma unroll
        for (int r = 0; r < 4; r++) gl[r * G_ + n] = acc[nt][r];
      }
    }
    __syncthreads();
    // cell update: one cell per thread
    unsigned short* g1s = (unsigned short*)g1l;
    int base = r_c * G_ + d_c;
    float ig = gl[base]        + bf16_f32(g1s[base]);
    float fg = gl[base + 128]  + bf16_f32(g1s[base + 128]);
    float gg = gl[base + 256]  + bf16_f32(g1s[base + 256]);
    float og = gl[base + 384]  + bf16_f32(g1s[base + 384]);
    float cn = sigm(fg) * c_st + sigm(ig) * tanh_f(gg);
    float hn = sigm(og) * tanh_f(cn);
    c_st = cn;
    out_e[((size_t)(b0 + r_c) * T_ + t) * D_ + d_c] = hn;
    *(unsigned short*)(hl + ((((unsigned)r_c << 8) + ((unsigned)d_c << 1)) ^ ((unsigned)r_c << 4))) = f32_bf16(hn);
    __syncthreads();
  }
}

extern "C" void kernel_launch(void* const* d_in, const int* in_sizes, int n_in,
                              void* d_out, int out_size, void* d_ws, size_t ws_size,
                              hipStream_t stream) {
  (void)in_sizes; (void)n_in; (void)out_size;
  const float* x    = (const float*)d_in[0];
  const float* Wa   = (const float*)d_in[1];
  // d_in[2] = ba : dead (softmax shift invariance); Wh/Wc parts of Wa also dead
  const float* W_ih = (const float*)d_in[3];
  const float* W_hh = (const float*)d_in[4];
  const float* b_ih = (const float*)d_in[5];
  const float* b_hh = (const float*)d_in[6];
  float* out_w = (float*)d_out;
  float* out_e = out_w + (size_t)B_ * T_ * D_;
  float* attn = (float*)d_ws;
  unsigned short* g1 = (unsigned short*)((char*)d_ws + (1 << 20));
  size_t need = (size_t)(1 << 20) + (size_t)T_ * B_ * G_ * 2;
  if (ws_size < need) return;   // would corrupt memory otherwise; shows as poison-fail

  k_attn <<<B_, 256, 0, stream>>>(x, Wa, attn);
  k_gemm1<<<256, 512, 131072, stream>>>(x, attn, W_ih, b_ih, b_hh, out_w, g1);
  k_rnn  <<<256, 512, 4096 + 8192 + 1024, stream>>>(W_hh, g1, out_e);
}